// Round 5
// baseline (279.240 us; speedup 1.0000x reference)
//
#include <hip/hip_runtime.h>
#include <stdint.h>

#define FN 16
#define FD 32
#define KC 16
#define BS 256
#define TS 48
#define CS 3000
#define VV 18
#define NW 96           // padded uint32 words per bit-row (94 used for 3000 bits)
#define NEG_BIG 10000000.0f

// ---------------- Kernel A: VQ codes per (n, j) ----------------
__global__ void k_codes(const float* __restrict__ tdata, const int* __restrict__ f_mask,
                        const float* __restrict__ centers, uint8_t* __restrict__ codes) {
    int idx = blockIdx.x * blockDim.x + threadIdx.x;   // n*16 + j
    if (idx >= BS * TS * FN) return;
    int j = idx & 15;
    const float* x = tdata + (size_t)idx * FD;
    float xv[FD];
    double xn = 0.0;
#pragma unroll
    for (int d = 0; d < FD; d++) { xv[d] = x[d]; xn += (double)xv[d] * xv[d]; }
    const float* cen = centers + (size_t)j * KC * FD;
    double best = 1e300; int bestk = 0;
    for (int k = 0; k < KC; k++) {
        double dot = 0.0, cn = 0.0;
#pragma unroll
        for (int d = 0; d < FD; d++) {
            float cv = cen[k * FD + d];
            dot += (double)xv[d] * cv;
            cn  += (double)cv * cv;
        }
        double dist = xn - 2.0 * dot + cn;
        if (dist < best) { best = dist; bestk = k; }   // first-min wins (matches argmin)
    }
    codes[idx] = f_mask[idx] ? (uint8_t)(bestk + 2) : (uint8_t)1;
}

// ---------------- any-over-t of f_mask per (b, i) ----------------
__global__ void k_anymask(const int* __restrict__ f_mask, uint8_t* __restrict__ anym) {
    int idx = blockIdx.x * blockDim.x + threadIdx.x;   // b*16 + i
    if (idx >= BS * FN) return;
    int i = idx & 15, b = idx >> 4;
    int any = 0;
    for (int t = 0; t < TS; t++) any |= f_mask[((size_t)b * TS + t) * FN + i];
    anym[idx] = any ? 1 : 0;
}

// ---------------- Kernel B: bit-pack patterns  M[i][j][v][cg] ----------------
__global__ void k_buildM(const int* __restrict__ pat, uint32_t* __restrict__ M) {
    int idx = blockIdx.x * blockDim.x + threadIdx.x;   // (i*16+j)*NW + cg
    if (idx >= FN * FN * NW) return;
    int cg = idx % NW;
    int ij = idx / NW;
    int j = ij & 15, i = ij >> 4;
    uint32_t w[VV];
#pragma unroll
    for (int v = 0; v < VV; v++) w[v] = 0u;
    int c0 = cg * 32;
    for (int cb = 0; cb < 32; cb++) {
        int c = c0 + cb;
        if (c >= CS) break;
        int p = pat[((size_t)i * CS + c) * FN + j];
        if (p == 0) {
#pragma unroll
            for (int v = 0; v < VV; v++) w[v] |= (1u << cb);   // wildcard matches all
        } else {
            w[p] |= (1u << cb);
        }
    }
    uint32_t* dst = M + (size_t)ij * VV * NW + cg;
#pragma unroll
    for (int v = 0; v < VV; v++) dst[(size_t)v * NW] = w[v];
}

// ---------------- Kernel C: pm bits per (i, b): OR_t AND_j M ----------------
__global__ void k_match(const uint8_t* __restrict__ codes, const uint32_t* __restrict__ M,
                        uint32_t* __restrict__ pm) {
    int b = blockIdx.x & 255;
    int i = blockIdx.x >> 8;
    int cg = threadIdx.x;                 // 96 threads (94 useful)
    __shared__ uint8_t cs[TS * FN];
    for (int k = threadIdx.x; k < TS * FN; k += blockDim.x)
        cs[k] = codes[(size_t)b * TS * FN + k];
    __syncthreads();
    const uint32_t* Mi = M + (size_t)i * FN * VV * NW;
    uint32_t acc = 0;
    for (int t = 0; t < TS; t++) {
        uint32_t m = 0xFFFFFFFFu;
#pragma unroll
        for (int jj = 0; jj < FN; jj++) {
            int v = cs[t * FN + jj];
            m &= Mi[((size_t)jj * VV + v) * NW + cg];
            if (!m) break;                // random patterns die fast (~3 ANDs)
        }
        acc |= m;
    }
    pm[(size_t)blockIdx.x * NW + cg] = acc;
}

// ---------------- Kernel E: per-(i,b) attention + rep ----------------
__global__ __launch_bounds__(256) void k_attn(
    const float* __restrict__ tdata, const float* __restrict__ pat_rep,
    const float* __restrict__ pos_cnt, const float* __restrict__ neg_cnt,
    const float* __restrict__ W_q, const float* __restrict__ b_q,
    const float* __restrict__ W_k, const float* __restrict__ b_k,
    const float* __restrict__ W_v, const float* __restrict__ b_v,
    const uint32_t* __restrict__ pm, const uint8_t* __restrict__ anym,
    float* __restrict__ out_a, float* __restrict__ out_rep)
{
    int b = blockIdx.x & 255;
    int i = blockIdx.x >> 8;
    int tid = threadIdx.x;

    __shared__ float e_s[CS];
    __shared__ float iq_s[FD];
    __shared__ float kq_s[FD + 1];
    __shared__ float s_sh[FD + 1];
    __shared__ float red[4];
    __shared__ float bkiq_s, maxv_s, sum_s;

    // iq = q_last[b,i] @ W_q[i].T + b_q[i]
    const float* q = tdata + (((size_t)b * TS + (TS - 1)) * FN + i) * FD;
    if (tid < FD) {
        float acc = b_q[i * FD + tid];
        const float* Wr = W_q + ((size_t)i * FD + tid) * FD;
#pragma unroll
        for (int e = 0; e < FD; e++) acc += q[e] * Wr[e];
        iq_s[tid] = acc;
    }
    if (tid < FD + 1) s_sh[tid] = 0.f;
    __syncthreads();
    // kq[e] = sum_d W_k[i][d][e] * iq[d]   (33-dim)
    if (tid < FD + 1) {
        float acc = 0.f;
        for (int d = 0; d < FD; d++)
            acc += W_k[((size_t)i * FD + d) * (FD + 1) + tid] * iq_s[d];
        kq_s[tid] = acc;
    }
    if (tid == 0) {
        float acc = 0.f;
        for (int d = 0; d < FD; d++) acc += b_k[i * FD + d] * iq_s[d];
        bkiq_s = acc;
    }
    __syncthreads();
    float bkiq = bkiq_s;

    const uint32_t* pmrow = pm + (size_t)blockIdx.x * NW;

    // pass 1: e values + max
    float lmax = -3.4e38f;
    for (int c = tid; c < CS; c += 256) {
        uint32_t bit = (pmrow[c >> 5] >> (c & 31)) & 1u;
        float e;
        if (bit) {
            const float* pr = pat_rep + ((size_t)i * CS + c) * FD;
            float acc = 0.f;
#pragma unroll
            for (int d = 0; d < FD; d++) acc += pr[d] * kq_s[d];
            float pc = pos_cnt[(size_t)i * CS + c], nc = neg_cnt[(size_t)i * CS + c];
            float ratio = pc / (pc + nc + 1e-6f);
            e = bkiq + acc + ratio * kq_s[FD];
        } else {
            e = bkiq - NEG_BIG;
        }
        e_s[c] = e;
        lmax = fmaxf(lmax, e);
    }
    for (int off = 32; off > 0; off >>= 1) lmax = fmaxf(lmax, __shfl_down(lmax, off));
    if ((tid & 63) == 0) red[tid >> 6] = lmax;
    __syncthreads();
    if (tid == 0) {
        float m = red[0];
        for (int w = 1; w < 4; w++) m = fmaxf(m, red[w]);
        maxv_s = m;
    }
    __syncthreads();
    float maxv = maxv_s;

    // pass 2: exp + sum
    float lsum = 0.f;
    for (int c = tid; c < CS; c += 256) {
        float ex = expf(e_s[c] - maxv);
        e_s[c] = ex;
        lsum += ex;
    }
    for (int off = 32; off > 0; off >>= 1) lsum += __shfl_down(lsum, off);
    if ((tid & 63) == 0) red[tid >> 6] = lsum;
    __syncthreads();
    if (tid == 0) sum_s = red[0] + red[1] + red[2] + red[3];
    __syncthreads();
    float sum = sum_s;

    // pass 3: a = ex/sum, write out, accumulate s = sum_c a*pm*aug[c]
    float* arow = out_a + (size_t)blockIdx.x * CS;
    for (int c = tid; c < CS; c += 256) {
        float a = e_s[c] / sum;
        arow[c] = a;
        uint32_t bit = (pmrow[c >> 5] >> (c & 31)) & 1u;
        if (bit) {
            const float* pr = pat_rep + ((size_t)i * CS + c) * FD;
            for (int f = 0; f < FD; f++) atomicAdd(&s_sh[f], a * pr[f]);
            float pc = pos_cnt[(size_t)i * CS + c], nc = neg_cnt[(size_t)i * CS + c];
            float ratio = pc / (pc + nc + 1e-6f);
            atomicAdd(&s_sh[FD], a * ratio);
        }
    }
    __syncthreads();

    // v = b_v + W_v @ s ; apply any-mask; write rep[b][i][:]
    if (tid < FD + 1) {
        float acc = b_v[(size_t)i * (FD + 1) + tid];
        const float* Wr = W_v + ((size_t)i * (FD + 1) + tid) * (FD + 1);
#pragma unroll
        for (int f = 0; f < FD + 1; f++) acc += Wr[f] * s_sh[f];
        float r = anym[b * FN + i] ? acc : 0.f;
        out_rep[((size_t)b * FN + i) * (FD + 1) + tid] = r;
    }
}

// ---------------- Kernel F: cali = rep_flat @ W_pred.T ----------------
__global__ void k_cali(const float* __restrict__ rep, const float* __restrict__ W_pred,
                       float* __restrict__ out) {
    int b = blockIdx.x * blockDim.x + threadIdx.x;
    if (b >= BS) return;
    const float* r = rep + (size_t)b * (FN * (FD + 1));
    for (int o = 0; o < 2; o++) {
        float acc = 0.f;
        const float* w = W_pred + (size_t)o * (FN * (FD + 1));
        for (int k = 0; k < FN * (FD + 1); k++) acc += r[k] * w[k];
        out[b * 2 + o] = acc;
    }
}

extern "C" void kernel_launch(void* const* d_in, const int* in_sizes, int n_in,
                              void* d_out, int out_size, void* d_ws, size_t ws_size,
                              hipStream_t stream) {
    const float* tdata   = (const float*)d_in[0];
    const int*   f_mask  = (const int*)d_in[1];     // bool -> int32 on device
    const float* centers = (const float*)d_in[2];
    const int*   pat     = (const int*)d_in[3];
    const float* pat_rep = (const float*)d_in[4];
    const float* pos_cnt = (const float*)d_in[5];
    const float* neg_cnt = (const float*)d_in[6];
    const float* W_q     = (const float*)d_in[7];
    const float* b_q     = (const float*)d_in[8];
    const float* W_k     = (const float*)d_in[9];
    const float* b_k     = (const float*)d_in[10];
    const float* W_v     = (const float*)d_in[11];
    const float* b_v     = (const float*)d_in[12];
    const float* W_pred  = (const float*)d_in[13];

    float* out = (float*)d_out;
    float* out_cali = out;                       // (256, 2)
    float* out_a    = out + 512;                 // (16, 256, 3000)
    float* out_rep  = out + 512 + FN * BS * CS;  // (256, 16, 33)

    char* ws = (char*)d_ws;
    uint8_t*  codes = (uint8_t*)ws;                               // 196608 B
    uint8_t*  anym  = (uint8_t*)(ws + 196608);                    // 4096 B
    uint32_t* M     = (uint32_t*)(ws + 200704);                   // 16*16*18*96*4 = 1769472 B
    uint32_t* pm    = (uint32_t*)(ws + 200704 + 1769472);         // 16*256*96*4 = 1572864 B

    hipLaunchKernelGGL(k_codes,   dim3((BS * TS * FN) / 256), dim3(256), 0, stream,
                       tdata, f_mask, centers, codes);
    hipLaunchKernelGGL(k_anymask, dim3((BS * FN + 255) / 256), dim3(256), 0, stream,
                       f_mask, anym);
    hipLaunchKernelGGL(k_buildM,  dim3((FN * FN * NW) / 256), dim3(256), 0, stream,
                       pat, M);
    hipLaunchKernelGGL(k_match,   dim3(FN * BS), dim3(NW), 0, stream,
                       codes, M, pm);
    hipLaunchKernelGGL(k_attn,    dim3(FN * BS), dim3(256), 0, stream,
                       tdata, pat_rep, pos_cnt, neg_cnt, W_q, b_q, W_k, b_k, W_v, b_v,
                       pm, anym, out_a, out_rep);
    hipLaunchKernelGGL(k_cali,    dim3(1), dim3(256), 0, stream,
                       out_rep, W_pred, out_cali);
}